// Round 1
// baseline (4175.175 us; speedup 1.0000x reference)
//
#include <hip/hip_runtime.h>
#include <stdint.h>

#define N_TOK 32768
#define DIM   768
#define NEXP  16
#define CAP   4096
#define FEXP  3072
#define FSH   1536

typedef __attribute__((ext_vector_type(8))) short short8;
typedef __attribute__((ext_vector_type(4))) float f32x4;

__device__ __forceinline__ void async16(const ushort* g, ushort* l) {
  __builtin_amdgcn_global_load_lds((const __attribute__((address_space(1))) uint32_t*)g,
                                   (__attribute__((address_space(3))) uint32_t*)l,
                                   16, 0, 0);
}

__device__ __forceinline__ ushort f2bf(float f) {
  uint32_t u = __float_as_uint(f);
  u += 0x7FFFu + ((u >> 16) & 1u);   // RNE
  return (ushort)(u >> 16);
}

// ---------------- fp32 -> bf16 ----------------
__global__ __launch_bounds__(256) void cvt_kernel(const float* __restrict__ in,
                                                  ushort* __restrict__ out, int n4) {
  int i = blockIdx.x * 256 + threadIdx.x;
  if (i >= n4) return;
  float4 v = reinterpret_cast<const float4*>(in)[i];
  ushort4 o = make_ushort4(f2bf(v.x), f2bf(v.y), f2bf(v.z), f2bf(v.w));
  reinterpret_cast<ushort4*>(out)[i] = o;
}

// ---------------- gate scores (fp64 for exact ranking) ----------------
__global__ __launch_bounds__(256) void gate_kernel(const float* __restrict__ X,
                                                   const float* __restrict__ GW,
                                                   float* __restrict__ scF,
                                                   double* __restrict__ scD) {
  __shared__ float gw[NEXP * (DIM + 4)];   // +4 pad: kills 16-way bank conflict
  int tid = threadIdx.x;
  for (int i = tid; i < NEXP * DIM / 4; i += 256) {
    int e = i / (DIM / 4);
    int k = (i % (DIM / 4)) * 4;
    float4 v = reinterpret_cast<const float4*>(GW)[i];
    float* d = &gw[e * (DIM + 4) + k];
    d[0] = v.x; d[1] = v.y; d[2] = v.z; d[3] = v.w;
  }
  __syncthreads();
  int tok = blockIdx.x * 16 + (tid >> 4);
  int e = tid & 15;
  const float4* x4 = reinterpret_cast<const float4*>(X + (size_t)tok * DIM);
  const float* g = &gw[e * (DIM + 4)];
  double acc = 0.0;
  for (int i = 0; i < DIM / 4; i++) {
    float4 v = x4[i];
    acc += (double)v.x * (double)g[i * 4 + 0] + (double)v.y * (double)g[i * 4 + 1]
         + (double)v.z * (double)g[i * 4 + 2] + (double)v.w * (double)g[i * 4 + 3];
  }
  double sd = 1.0 / (1.0 + exp(-acc));
  scD[(size_t)e * N_TOK + tok] = sd;
  scF[(size_t)e * N_TOK + tok] = (float)sd;
}

// ---------------- per-expert top-CAP radix select ----------------
__global__ __launch_bounds__(1024) void select_kernel(const float* __restrict__ scF,
                                                      const double* __restrict__ scD,
                                                      int* __restrict__ idxOut,
                                                      float* __restrict__ wscOut) {
  int e = blockIdx.x;
  const float* s = scF + (size_t)e * N_TOK;
  const double* sd = scD + (size_t)e * N_TOK;
  __shared__ unsigned hist[2048];
  __shared__ unsigned cgt[1024];
  __shared__ int eqIdx[512];
  __shared__ unsigned sB1, sB2, sNeed, sT, sM, sCntEq, eqCnt;
  int tid = threadIdx.x;

#define KEY(b) (((b) & 0x80000000u) ? ~(b) : ((b) | 0x80000000u))

  // pass 1: top 11 bits
  hist[tid] = 0; hist[tid + 1024] = 0;
  __syncthreads();
  for (int i = 0; i < N_TOK / 1024; i++) {
    unsigned b = __float_as_uint(s[i * 1024 + tid]);
    unsigned u = KEY(b);
    atomicAdd(&hist[u >> 21], 1u);
  }
  __syncthreads();
  if (tid == 0) {
    unsigned need = CAP, acc = 0; int b;
    for (b = 2047; b >= 0; b--) { if (acc + hist[b] >= need) break; acc += hist[b]; }
    sB1 = (unsigned)b; sNeed = need - acc;
  }
  __syncthreads();
  unsigned b1 = sB1;
  __syncthreads();
  // pass 2: mid 11 bits
  hist[tid] = 0; hist[tid + 1024] = 0;
  __syncthreads();
  for (int i = 0; i < N_TOK / 1024; i++) {
    unsigned b = __float_as_uint(s[i * 1024 + tid]);
    unsigned u = KEY(b);
    if ((u >> 21) == b1) atomicAdd(&hist[(u >> 10) & 0x7FFu], 1u);
  }
  __syncthreads();
  if (tid == 0) {
    unsigned need = sNeed, acc = 0; int b;
    for (b = 2047; b >= 0; b--) { if (acc + hist[b] >= need) break; acc += hist[b]; }
    sB2 = (unsigned)b; sNeed = need - acc;
  }
  __syncthreads();
  unsigned b2 = sB2;
  unsigned pref = (b1 << 11) | b2;
  __syncthreads();
  // pass 3: low 10 bits
  hist[tid] = 0; hist[tid + 1024] = 0;
  __syncthreads();
  for (int i = 0; i < N_TOK / 1024; i++) {
    unsigned b = __float_as_uint(s[i * 1024 + tid]);
    unsigned u = KEY(b);
    if ((u >> 10) == pref) atomicAdd(&hist[u & 0x3FFu], 1u);
  }
  __syncthreads();
  if (tid == 0) {
    unsigned need = sNeed, acc = 0; int b;
    for (b = 1023; b >= 0; b--) { if (acc + hist[b] >= need) break; acc += hist[b]; }
    sT = (b1 << 21) | (b2 << 10) | (unsigned)b;
    sM = need - acc;
    sCntEq = hist[b];
    eqCnt = 0;
  }
  __syncthreads();
  unsigned T = sT, m = sM, cntEq = sCntEq;
  unsigned G = CAP - m;

  // deterministic compaction of u > T (set semantics; slot order irrelevant)
  int base = tid * (N_TOK / 1024);
  unsigned lg = 0;
  for (int i = 0; i < N_TOK / 1024; i++) {
    unsigned b = __float_as_uint(s[base + i]);
    unsigned u = KEY(b);
    lg += (u > T) ? 1u : 0u;
  }
  cgt[tid] = lg;
  __syncthreads();
  if (tid == 0) {
    unsigned a = 0;
    for (int i = 0; i < 1024; i++) { unsigned t = cgt[i]; cgt[i] = a; a += t; }
  }
  __syncthreads();
  unsigned og = cgt[tid];
  for (int i = 0; i < N_TOK / 1024; i++) {
    int t = base + i;
    float v = s[t];
    unsigned b = __float_as_uint(v);
    unsigned u = KEY(b);
    if (u > T) {
      idxOut[e * CAP + og] = t; wscOut[e * CAP + og] = v; og++;
    } else if (u == T && cntEq <= 512) {
      unsigned p = atomicAdd(&eqCnt, 1u);
      eqIdx[p] = t;
    }
  }
  __syncthreads();
  // boundary group: rank by fp64 score (desc), then index (asc) — matches top_k
  if (cntEq <= 512) {
    if (tid < cntEq) {
      int ti = eqIdx[tid];
      double di = sd[ti];
      unsigned rank = 0;
      for (unsigned j = 0; j < cntEq; j++) {
        int tj = eqIdx[j];
        double dj = sd[tj];
        if (dj > di || (dj == di && tj < ti)) rank++;
      }
      if (rank < m) { idxOut[e * CAP + G + rank] = ti; wscOut[e * CAP + G + rank] = s[ti]; }
    }
  } else {
    if (tid == 0) {  // pathological mass-tie: index order
      unsigned c = 0;
      for (int t = 0; t < N_TOK && c < m; t++) {
        unsigned b = __float_as_uint(s[t]);
        unsigned u = KEY(b);
        if (u == T) { idxOut[e * CAP + G + c] = t; wscOut[e * CAP + G + c] = s[t]; c++; }
      }
    }
  }
#undef KEY
}

// ---------------- fused gate+up GEMM: H = bf16(silu(X Wg^T) * (X Wu^T)) ----------------
// 128x128 tile, BK=64, 256 thr (2x2 waves of 64x64), 16x16x32 bf16 MFMA.
// LDS layout: 16B cells, cell = chunk*128 + row (chunk = k/8) -> 2-way-only bank aliasing.
__global__ __launch_bounds__(256, 2) void gemm_up_kernel(
    const ushort* __restrict__ X, const int* __restrict__ idx,
    const ushort* __restrict__ Wg, const ushort* __restrict__ Wu,
    ushort* __restrict__ H,
    int K, int Ntot, int mbase,
    long long idxStrideZ, long long wStrideZ, long long hStrideZ) {
  __shared__ ushort lA[128 * 64];
  __shared__ ushort lBg[128 * 64];
  __shared__ ushort lBu[128 * 64];
  int tid = threadIdx.x, lane = tid & 63, wave = tid >> 6;
  int z = blockIdx.z;
  const int* idx_e = idx ? idx + (size_t)z * idxStrideZ : (const int*)0;
  const ushort* Wg_e = Wg + (size_t)z * wStrideZ;
  const ushort* Wu_e = Wu + (size_t)z * wStrideZ;
  ushort* H_e = H + (size_t)z * hStrideZ;

  const ushort* ap[4]; const ushort* bgp[4]; const ushort* bup[4];
  int lo[4];
#pragma unroll
  for (int j = 0; j < 4; j++) {
    int wj = wave * 4 + j;
    int chunk = wj >> 1;
    int rowt = ((wj & 1) << 6) + lane;
    int gRow = blockIdx.y * 128 + rowt;
    int aRow = idx_e ? idx_e[mbase + gRow] : (mbase + gRow);
    ap[j] = X + (size_t)aRow * K + chunk * 8;
    int bRow = blockIdx.x * 128 + rowt;
    bgp[j] = Wg_e + (size_t)bRow * K + chunk * 8;
    bup[j] = Wu_e + (size_t)bRow * K + chunk * 8;
    lo[j] = wj * 512;  // cellbase(wj*64) * 8 ushorts
  }
  int wm = (wave >> 1) * 64, wn = (wave & 1) * 64;
  f32x4 zero = {0.f, 0.f, 0.f, 0.f};
  f32x4 accg[4][4], accu[4][4];
#pragma unroll
  for (int a = 0; a < 4; a++)
#pragma unroll
    for (int b = 0; b < 4; b++) { accg[a][b] = zero; accu[a][b] = zero; }

  for (int kt = 0; kt < K; kt += 64) {
    __syncthreads();
#pragma unroll
    for (int j = 0; j < 4; j++) {
      async16(ap[j], &lA[lo[j]]);
      async16(bgp[j], &lBg[lo[j]]);
      async16(bup[j], &lBu[lo[j]]);
      ap[j] += 64; bgp[j] += 64; bup[j] += 64;
    }
    __syncthreads();  // compiler emits vmcnt(0) drain before barrier
#pragma unroll
    for (int kk = 0; kk < 2; kk++) {
      int cb = (kk * 4 + (lane >> 4)) * 128;
      short8 a[4], bg[4], bu[4];
#pragma unroll
      for (int mt = 0; mt < 4; mt++)
        a[mt] = *(const short8*)&lA[(cb + wm + mt * 16 + (lane & 15)) * 8];
#pragma unroll
      for (int nt = 0; nt < 4; nt++) {
        bg[nt] = *(const short8*)&lBg[(cb + wn + nt * 16 + (lane & 15)) * 8];
        bu[nt] = *(const short8*)&lBu[(cb + wn + nt * 16 + (lane & 15)) * 8];
      }
#pragma unroll
      for (int mt = 0; mt < 4; mt++)
#pragma unroll
        for (int nt = 0; nt < 4; nt++) {
          accg[mt][nt] = __builtin_amdgcn_mfma_f32_16x16x32_bf16(a[mt], bg[nt], accg[mt][nt], 0, 0, 0);
          accu[mt][nt] = __builtin_amdgcn_mfma_f32_16x16x32_bf16(a[mt], bu[nt], accu[mt][nt], 0, 0, 0);
        }
    }
  }
#pragma unroll
  for (int mt = 0; mt < 4; mt++)
#pragma unroll
    for (int nt = 0; nt < 4; nt++)
#pragma unroll
      for (int r = 0; r < 4; r++) {
        int row = blockIdx.y * 128 + wm + mt * 16 + ((lane >> 4) << 2) + r;
        int col = blockIdx.x * 128 + wn + nt * 16 + (lane & 15);
        float g = accg[mt][nt][r], u = accu[mt][nt][r];
        float h = (g / (1.f + expf(-g))) * u;   // silu(g)*u
        H_e[(size_t)row * Ntot + col] = f2bf(h);
      }
}

// ---------------- down GEMM: Y (+)= score * (H Wd^T) ----------------
__global__ __launch_bounds__(256, 2) void gemm_down_kernel(
    const ushort* __restrict__ H, const ushort* __restrict__ W,
    float* __restrict__ Y,
    const int* __restrict__ idx, const float* __restrict__ wsc,
    int K, int mbase,
    long long hStrideZ, long long wStrideZ, long long idxStrideZ) {
  __shared__ ushort lA[128 * 64];
  __shared__ ushort lB[128 * 64];
  __shared__ int sIdx[128];
  __shared__ float sSc[128];
  int tid = threadIdx.x, lane = tid & 63, wave = tid >> 6;
  int z = blockIdx.z;
  const ushort* H_e = H + (size_t)z * hStrideZ;
  const ushort* W_e = W + (size_t)z * wStrideZ;
  if (idx && tid < 128) {
    size_t ib = (size_t)z * idxStrideZ + mbase + blockIdx.y * 128 + tid;
    sIdx[tid] = idx[ib];
    sSc[tid] = wsc[ib];
  }
  const ushort* ap[4]; const ushort* bp[4]; int lo[4];
#pragma unroll
  for (int j = 0; j < 4; j++) {
    int wj = wave * 4 + j;
    int chunk = wj >> 1;
    int rowt = ((wj & 1) << 6) + lane;
    ap[j] = H_e + (size_t)(blockIdx.y * 128 + rowt) * K + chunk * 8;
    bp[j] = W_e + (size_t)(blockIdx.x * 128 + rowt) * K + chunk * 8;
    lo[j] = wj * 512;
  }
  int wm = (wave >> 1) * 64, wn = (wave & 1) * 64;
  f32x4 zero = {0.f, 0.f, 0.f, 0.f};
  f32x4 acc[4][4];
#pragma unroll
  for (int a = 0; a < 4; a++)
#pragma unroll
    for (int b = 0; b < 4; b++) acc[a][b] = zero;

  for (int kt = 0; kt < K; kt += 64) {
    __syncthreads();
#pragma unroll
    for (int j = 0; j < 4; j++) {
      async16(ap[j], &lA[lo[j]]);
      async16(bp[j], &lB[lo[j]]);
      ap[j] += 64; bp[j] += 64;
    }
    __syncthreads();
#pragma unroll
    for (int kk = 0; kk < 2; kk++) {
      int cb = (kk * 4 + (lane >> 4)) * 128;
      short8 a[4], b[4];
#pragma unroll
      for (int mt = 0; mt < 4; mt++)
        a[mt] = *(const short8*)&lA[(cb + wm + mt * 16 + (lane & 15)) * 8];
#pragma unroll
      for (int nt = 0; nt < 4; nt++)
        b[nt] = *(const short8*)&lB[(cb + wn + nt * 16 + (lane & 15)) * 8];
#pragma unroll
      for (int mt = 0; mt < 4; mt++)
#pragma unroll
        for (int nt = 0; nt < 4; nt++)
          acc[mt][nt] = __builtin_amdgcn_mfma_f32_16x16x32_bf16(a[mt], b[nt], acc[mt][nt], 0, 0, 0);
    }
  }
#pragma unroll
  for (int mt = 0; mt < 4; mt++)
#pragma unroll
    for (int nt = 0; nt < 4; nt++)
#pragma unroll
      for (int r = 0; r < 4; r++) {
        int row = wm + mt * 16 + ((lane >> 4) << 2) + r;
        int col = blockIdx.x * 128 + wn + nt * 16 + (lane & 15);
        float v = acc[mt][nt][r];
        if (idx) {
          atomicAdd(&Y[(size_t)sIdx[row] * DIM + col], v * sSc[row]);
        } else {
          Y[(size_t)(mbase + blockIdx.y * 128 + row) * DIM + col] = v;
        }
      }
}

// ---------------- host ----------------
extern "C" void kernel_launch(void* const* d_in, const int* in_sizes, int n_in,
                              void* d_out, int out_size, void* d_ws, size_t ws_size,
                              hipStream_t stream) {
  (void)in_sizes; (void)n_in; (void)out_size;
  const float* hs  = (const float*)d_in[0];
  const float* gw  = (const float*)d_in[1];
  const float* Wg  = (const float*)d_in[2];
  const float* Wu  = (const float*)d_in[3];
  const float* Wd  = (const float*)d_in[4];
  const float* Wsg = (const float*)d_in[5];
  const float* Wsu = (const float*)d_in[6];
  const float* Wsd = (const float*)d_in[7];
  float* Y = (float*)d_out;

  char* p = (char*)d_ws;
  auto carve = [&](size_t bytes) {
    char* r = p;
    p += (bytes + 255) & ~(size_t)255;
    return r;
  };
  ushort* Xb   = (ushort*)carve((size_t)N_TOK * DIM * 2);
  ushort* Wgb  = (ushort*)carve((size_t)NEXP * FEXP * DIM * 2);
  ushort* Wub  = (ushort*)carve((size_t)NEXP * FEXP * DIM * 2);
  ushort* Wdb  = (ushort*)carve((size_t)NEXP * DIM * FEXP * 2);
  ushort* Wsgb = (ushort*)carve((size_t)FSH * DIM * 2);
  ushort* Wsub = (ushort*)carve((size_t)FSH * DIM * 2);
  ushort* Wsdb = (ushort*)carve((size_t)DIM * FSH * 2);
  float*  scF  = (float*)carve((size_t)NEXP * N_TOK * 4);
  double* scD  = (double*)carve((size_t)NEXP * N_TOK * 8);
  int*    idx  = (int*)carve((size_t)NEXP * CAP * 4);
  float*  wsc  = (float*)carve((size_t)NEXP * CAP * 4);
  size_t used = (size_t)(p - (char*)d_ws);
  size_t hbytes = ws_size > used ? ws_size - used : 0;
  ushort* Hbuf = (ushort*)p;

  auto cvt = [&](const float* a, ushort* b, size_t n) {
    int n4 = (int)(n / 4);
    cvt_kernel<<<(n4 + 255) / 256, 256, 0, stream>>>(a, b, n4);
  };
  cvt(hs,  Xb,   (size_t)N_TOK * DIM);
  cvt(Wg,  Wgb,  (size_t)NEXP * FEXP * DIM);
  cvt(Wu,  Wub,  (size_t)NEXP * FEXP * DIM);
  cvt(Wd,  Wdb,  (size_t)NEXP * DIM * FEXP);
  cvt(Wsg, Wsgb, (size_t)FSH * DIM);
  cvt(Wsu, Wsub, (size_t)FSH * DIM);
  cvt(Wsd, Wsdb, (size_t)DIM * FSH);

  gate_kernel<<<N_TOK / 16, 256, 0, stream>>>(hs, gw, scF, scD);
  select_kernel<<<NEXP, 1024, 0, stream>>>(scF, scD, idx, wsc);

  // shared expert first: plain stores initialize Y (poisoned 0xAA) before expert atomics
  size_t maxRowsSh = hbytes / ((size_t)FSH * 2);
  int mcSh = (int)(maxRowsSh > (size_t)N_TOK ? (size_t)N_TOK : maxRowsSh);
  mcSh = (mcSh / 128) * 128;
  if (mcSh < 128) mcSh = 128;
  for (int mb = 0; mb < N_TOK; mb += mcSh) {
    int mc = (N_TOK - mb) < mcSh ? (N_TOK - mb) : mcSh;
    gemm_up_kernel<<<dim3(FSH / 128, mc / 128, 1), 256, 0, stream>>>(
        Xb, (const int*)0, Wsgb, Wsub, Hbuf, DIM, FSH, mb, 0, 0, 0);
    gemm_down_kernel<<<dim3(6, mc / 128, 1), 256, 0, stream>>>(
        Hbuf, Wsdb, Y, (const int*)0, (const float*)0, FSH, mb, 0, 0, 0);
  }

  // routed experts
  size_t needAll = (size_t)NEXP * CAP * FEXP * 2;
  if (hbytes >= needAll) {
    gemm_up_kernel<<<dim3(FEXP / 128, CAP / 128, NEXP), 256, 0, stream>>>(
        Xb, idx, Wgb, Wub, Hbuf, DIM, FEXP, 0,
        (long long)CAP, (long long)FEXP * DIM, (long long)CAP * FEXP);
    gemm_down_kernel<<<dim3(6, CAP / 128, NEXP), 256, 0, stream>>>(
        Hbuf, Wdb, Y, idx, wsc, FEXP, 0,
        (long long)CAP * FEXP, (long long)DIM * FEXP, (long long)CAP);
  } else {
    size_t maxRowsE = hbytes / ((size_t)FEXP * 2);
    int mcE = (int)(maxRowsE > (size_t)CAP ? (size_t)CAP : maxRowsE);
    mcE = (mcE / 128) * 128;
    if (mcE < 128) mcE = 128;
    for (int e = 0; e < NEXP; e++) {
      for (int mb = 0; mb < CAP; mb += mcE) {
        int mc = (CAP - mb) < mcE ? (CAP - mb) : mcE;
        gemm_up_kernel<<<dim3(FEXP / 128, mc / 128, 1), 256, 0, stream>>>(
            Xb, idx + (size_t)e * CAP, Wgb + (size_t)e * FEXP * DIM,
            Wub + (size_t)e * FEXP * DIM, Hbuf, DIM, FEXP, mb, 0, 0, 0);
        gemm_down_kernel<<<dim3(6, mc / 128, 1), 256, 0, stream>>>(
            Hbuf, Wdb + (size_t)e * DIM * FEXP, Y, idx + (size_t)e * CAP,
            wsc + (size_t)e * CAP, FEXP, mb, 0, 0, 0);
      }
    }
  }
}

// Round 2
// 3242.241 us; speedup vs baseline: 1.2877x; 1.2877x over previous
//
#include <hip/hip_runtime.h>
#include <stdint.h>

#define N_TOK 32768
#define DIM   768
#define NEXP  16
#define CAP   4096
#define FEXP  3072
#define FSH   1536

typedef __attribute__((ext_vector_type(8))) short short8;
typedef __attribute__((ext_vector_type(4))) float f32x4;

__device__ __forceinline__ void async16(const ushort* g, ushort* l) {
  __builtin_amdgcn_global_load_lds((const __attribute__((address_space(1))) uint32_t*)g,
                                   (__attribute__((address_space(3))) uint32_t*)l,
                                   16, 0, 0);
}

__device__ __forceinline__ ushort f2bf(float f) {
  uint32_t u = __float_as_uint(f);
  u += 0x7FFFu + ((u >> 16) & 1u);   // RNE
  return (ushort)(u >> 16);
}

// ---------------- fp32 -> bf16 ----------------
__global__ __launch_bounds__(256) void cvt_kernel(const float* __restrict__ in,
                                                  ushort* __restrict__ out, int n4) {
  int i = blockIdx.x * 256 + threadIdx.x;
  if (i >= n4) return;
  float4 v = reinterpret_cast<const float4*>(in)[i];
  ushort4 o = make_ushort4(f2bf(v.x), f2bf(v.y), f2bf(v.z), f2bf(v.w));
  reinterpret_cast<ushort4*>(out)[i] = o;
}

// ---------------- gate scores (fp64 for exact ranking) ----------------
__global__ __launch_bounds__(256) void gate_kernel(const float* __restrict__ X,
                                                   const float* __restrict__ GW,
                                                   float* __restrict__ scF,
                                                   double* __restrict__ scD) {
  __shared__ float gw[NEXP * (DIM + 4)];   // +4 pad: kills 16-way bank conflict
  int tid = threadIdx.x;
  for (int i = tid; i < NEXP * DIM / 4; i += 256) {
    int e = i / (DIM / 4);
    int k = (i % (DIM / 4)) * 4;
    float4 v = reinterpret_cast<const float4*>(GW)[i];
    float* d = &gw[e * (DIM + 4) + k];
    d[0] = v.x; d[1] = v.y; d[2] = v.z; d[3] = v.w;
  }
  __syncthreads();
  int tok = blockIdx.x * 16 + (tid >> 4);
  int e = tid & 15;
  const float4* x4 = reinterpret_cast<const float4*>(X + (size_t)tok * DIM);
  const float* g = &gw[e * (DIM + 4)];
  double acc = 0.0;
  for (int i = 0; i < DIM / 4; i++) {
    float4 v = x4[i];
    acc += (double)v.x * (double)g[i * 4 + 0] + (double)v.y * (double)g[i * 4 + 1]
         + (double)v.z * (double)g[i * 4 + 2] + (double)v.w * (double)g[i * 4 + 3];
  }
  double sd = 1.0 / (1.0 + exp(-acc));
  scD[(size_t)e * N_TOK + tok] = sd;
  scF[(size_t)e * N_TOK + tok] = (float)sd;
}

// ---------------- per-expert top-CAP radix select ----------------
__global__ __launch_bounds__(1024) void select_kernel(const float* __restrict__ scF,
                                                      const double* __restrict__ scD,
                                                      int* __restrict__ idxOut,
                                                      float* __restrict__ wscOut) {
  int e = blockIdx.x;
  const float* s = scF + (size_t)e * N_TOK;
  const double* sd = scD + (size_t)e * N_TOK;
  __shared__ unsigned hist[2048];
  __shared__ unsigned cgt[1024];
  __shared__ int eqIdx[512];
  __shared__ unsigned sB1, sB2, sNeed, sT, sM, sCntEq, eqCnt;
  int tid = threadIdx.x;

#define KEY(b) (((b) & 0x80000000u) ? ~(b) : ((b) | 0x80000000u))

  // pass 1: top 11 bits
  hist[tid] = 0; hist[tid + 1024] = 0;
  __syncthreads();
  for (int i = 0; i < N_TOK / 1024; i++) {
    unsigned b = __float_as_uint(s[i * 1024 + tid]);
    unsigned u = KEY(b);
    atomicAdd(&hist[u >> 21], 1u);
  }
  __syncthreads();
  if (tid == 0) {
    unsigned need = CAP, acc = 0; int b;
    for (b = 2047; b >= 0; b--) { if (acc + hist[b] >= need) break; acc += hist[b]; }
    sB1 = (unsigned)b; sNeed = need - acc;
  }
  __syncthreads();
  unsigned b1 = sB1;
  __syncthreads();
  // pass 2: mid 11 bits
  hist[tid] = 0; hist[tid + 1024] = 0;
  __syncthreads();
  for (int i = 0; i < N_TOK / 1024; i++) {
    unsigned b = __float_as_uint(s[i * 1024 + tid]);
    unsigned u = KEY(b);
    if ((u >> 21) == b1) atomicAdd(&hist[(u >> 10) & 0x7FFu], 1u);
  }
  __syncthreads();
  if (tid == 0) {
    unsigned need = sNeed, acc = 0; int b;
    for (b = 2047; b >= 0; b--) { if (acc + hist[b] >= need) break; acc += hist[b]; }
    sB2 = (unsigned)b; sNeed = need - acc;
  }
  __syncthreads();
  unsigned b2 = sB2;
  unsigned pref = (b1 << 11) | b2;
  __syncthreads();
  // pass 3: low 10 bits
  hist[tid] = 0; hist[tid + 1024] = 0;
  __syncthreads();
  for (int i = 0; i < N_TOK / 1024; i++) {
    unsigned b = __float_as_uint(s[i * 1024 + tid]);
    unsigned u = KEY(b);
    if ((u >> 10) == pref) atomicAdd(&hist[u & 0x3FFu], 1u);
  }
  __syncthreads();
  if (tid == 0) {
    unsigned need = sNeed, acc = 0; int b;
    for (b = 1023; b >= 0; b--) { if (acc + hist[b] >= need) break; acc += hist[b]; }
    sT = (b1 << 21) | (b2 << 10) | (unsigned)b;
    sM = need - acc;
    sCntEq = hist[b];
    eqCnt = 0;
  }
  __syncthreads();
  unsigned T = sT, m = sM, cntEq = sCntEq;
  unsigned G = CAP - m;

  // deterministic compaction of u > T (set semantics; slot order irrelevant)
  int base = tid * (N_TOK / 1024);
  unsigned lg = 0;
  for (int i = 0; i < N_TOK / 1024; i++) {
    unsigned b = __float_as_uint(s[base + i]);
    unsigned u = KEY(b);
    lg += (u > T) ? 1u : 0u;
  }
  cgt[tid] = lg;
  __syncthreads();
  if (tid == 0) {
    unsigned a = 0;
    for (int i = 0; i < 1024; i++) { unsigned t = cgt[i]; cgt[i] = a; a += t; }
  }
  __syncthreads();
  unsigned og = cgt[tid];
  for (int i = 0; i < N_TOK / 1024; i++) {
    int t = base + i;
    float v = s[t];
    unsigned b = __float_as_uint(v);
    unsigned u = KEY(b);
    if (u > T) {
      idxOut[e * CAP + og] = t; wscOut[e * CAP + og] = v; og++;
    } else if (u == T && cntEq <= 512) {
      unsigned p = atomicAdd(&eqCnt, 1u);
      eqIdx[p] = t;
    }
  }
  __syncthreads();
  // boundary group: rank by fp64 score (desc), then index (asc) — matches top_k
  if (cntEq <= 512) {
    if (tid < cntEq) {
      int ti = eqIdx[tid];
      double di = sd[ti];
      unsigned rank = 0;
      for (unsigned j = 0; j < cntEq; j++) {
        int tj = eqIdx[j];
        double dj = sd[tj];
        if (dj > di || (dj == di && tj < ti)) rank++;
      }
      if (rank < m) { idxOut[e * CAP + G + rank] = ti; wscOut[e * CAP + G + rank] = s[ti]; }
    }
  } else {
    if (tid == 0) {  // pathological mass-tie: index order
      unsigned c = 0;
      for (int t = 0; t < N_TOK && c < m; t++) {
        unsigned b = __float_as_uint(s[t]);
        unsigned u = KEY(b);
        if (u == T) { idxOut[e * CAP + G + c] = t; wscOut[e * CAP + G + c] = s[t]; c++; }
      }
    }
  }
#undef KEY
}

// ---------------- fused gate+up GEMM: H = bf16(silu(X Wg^T) * (X Wu^T)) ----------------
// 128x128 tile, BK=64, 256 thr (2x2 waves of 64x64), 16x16x32 bf16 MFMA.
// LDS layout: 16B cells, cell = chunk*128 + row (chunk = k/8) -> 2-way-only bank aliasing.
// TAG: 0 = shared-expert instance, 1 = routed-expert instance (profiling visibility only).
template <int TAG>
__global__ __launch_bounds__(256, 2) void gemm_up_t(
    const ushort* __restrict__ X, const int* __restrict__ idx,
    const ushort* __restrict__ Wg, const ushort* __restrict__ Wu,
    ushort* __restrict__ H,
    int K, int Ntot, int mbase,
    long long idxStrideZ, long long wStrideZ, long long hStrideZ) {
  __shared__ ushort lA[128 * 64];
  __shared__ ushort lBg[128 * 64];
  __shared__ ushort lBu[128 * 64];
  int tid = threadIdx.x, lane = tid & 63, wave = tid >> 6;
  int z = blockIdx.z;
  const int* idx_e = idx ? idx + (size_t)z * idxStrideZ : (const int*)0;
  const ushort* Wg_e = Wg + (size_t)z * wStrideZ;
  const ushort* Wu_e = Wu + (size_t)z * wStrideZ;
  ushort* H_e = H + (size_t)z * hStrideZ;

  const ushort* ap[4]; const ushort* bgp[4]; const ushort* bup[4];
  int lo[4];
#pragma unroll
  for (int j = 0; j < 4; j++) {
    int wj = wave * 4 + j;
    int chunk = wj >> 1;
    int rowt = ((wj & 1) << 6) + lane;
    int gRow = blockIdx.y * 128 + rowt;
    int aRow = idx_e ? idx_e[mbase + gRow] : (mbase + gRow);
    ap[j] = X + (size_t)aRow * K + chunk * 8;
    int bRow = blockIdx.x * 128 + rowt;
    bgp[j] = Wg_e + (size_t)bRow * K + chunk * 8;
    bup[j] = Wu_e + (size_t)bRow * K + chunk * 8;
    lo[j] = wj * 512;  // cellbase(wj*64) * 8 ushorts
  }
  int wm = (wave >> 1) * 64, wn = (wave & 1) * 64;
  f32x4 zero = {0.f, 0.f, 0.f, 0.f};
  f32x4 accg[4][4], accu[4][4];
#pragma unroll
  for (int a = 0; a < 4; a++)
#pragma unroll
    for (int b = 0; b < 4; b++) { accg[a][b] = zero; accu[a][b] = zero; }

  for (int kt = 0; kt < K; kt += 64) {
    __syncthreads();
#pragma unroll
    for (int j = 0; j < 4; j++) {
      async16(ap[j], &lA[lo[j]]);
      async16(bgp[j], &lBg[lo[j]]);
      async16(bup[j], &lBu[lo[j]]);
      ap[j] += 64; bgp[j] += 64; bup[j] += 64;
    }
    __syncthreads();  // compiler emits vmcnt(0) drain before barrier
#pragma unroll
    for (int kk = 0; kk < 2; kk++) {
      int cb = (kk * 4 + (lane >> 4)) * 128;
      short8 a[4], bg[4], bu[4];
#pragma unroll
      for (int mt = 0; mt < 4; mt++)
        a[mt] = *(const short8*)&lA[(cb + wm + mt * 16 + (lane & 15)) * 8];
#pragma unroll
      for (int nt = 0; nt < 4; nt++) {
        bg[nt] = *(const short8*)&lBg[(cb + wn + nt * 16 + (lane & 15)) * 8];
        bu[nt] = *(const short8*)&lBu[(cb + wn + nt * 16 + (lane & 15)) * 8];
      }
#pragma unroll
      for (int mt = 0; mt < 4; mt++)
#pragma unroll
        for (int nt = 0; nt < 4; nt++) {
          accg[mt][nt] = __builtin_amdgcn_mfma_f32_16x16x32_bf16(a[mt], bg[nt], accg[mt][nt], 0, 0, 0);
          accu[mt][nt] = __builtin_amdgcn_mfma_f32_16x16x32_bf16(a[mt], bu[nt], accu[mt][nt], 0, 0, 0);
        }
    }
  }
#pragma unroll
  for (int mt = 0; mt < 4; mt++)
#pragma unroll
    for (int nt = 0; nt < 4; nt++)
#pragma unroll
      for (int r = 0; r < 4; r++) {
        int row = blockIdx.y * 128 + wm + mt * 16 + ((lane >> 4) << 2) + r;
        int col = blockIdx.x * 128 + wn + nt * 16 + (lane & 15);
        float g = accg[mt][nt][r], u = accu[mt][nt][r];
        float h = (g / (1.f + expf(-g))) * u;   // silu(g)*u
        H_e[(size_t)row * Ntot + col] = f2bf(h);
      }
}

// ---------------- down GEMM: Y (+)= score * (H Wd^T) ----------------
template <int TAG>
__global__ __launch_bounds__(256, 2) void gemm_down_t(
    const ushort* __restrict__ H, const ushort* __restrict__ W,
    float* __restrict__ Y,
    const int* __restrict__ idx, const float* __restrict__ wsc,
    int K, int mbase,
    long long hStrideZ, long long wStrideZ, long long idxStrideZ) {
  __shared__ ushort lA[128 * 64];
  __shared__ ushort lB[128 * 64];
  __shared__ int sIdx[128];
  __shared__ float sSc[128];
  int tid = threadIdx.x, lane = tid & 63, wave = tid >> 6;
  int z = blockIdx.z;
  const ushort* H_e = H + (size_t)z * hStrideZ;
  const ushort* W_e = W + (size_t)z * wStrideZ;
  if (idx && tid < 128) {
    size_t ib = (size_t)z * idxStrideZ + mbase + blockIdx.y * 128 + tid;
    sIdx[tid] = idx[ib];
    sSc[tid] = wsc[ib];
  }
  const ushort* ap[4]; const ushort* bp[4]; int lo[4];
#pragma unroll
  for (int j = 0; j < 4; j++) {
    int wj = wave * 4 + j;
    int chunk = wj >> 1;
    int rowt = ((wj & 1) << 6) + lane;
    ap[j] = H_e + (size_t)(blockIdx.y * 128 + rowt) * K + chunk * 8;
    bp[j] = W_e + (size_t)(blockIdx.x * 128 + rowt) * K + chunk * 8;
    lo[j] = wj * 512;
  }
  int wm = (wave >> 1) * 64, wn = (wave & 1) * 64;
  f32x4 zero = {0.f, 0.f, 0.f, 0.f};
  f32x4 acc[4][4];
#pragma unroll
  for (int a = 0; a < 4; a++)
#pragma unroll
    for (int b = 0; b < 4; b++) acc[a][b] = zero;

  for (int kt = 0; kt < K; kt += 64) {
    __syncthreads();
#pragma unroll
    for (int j = 0; j < 4; j++) {
      async16(ap[j], &lA[lo[j]]);
      async16(bp[j], &lB[lo[j]]);
      ap[j] += 64; bp[j] += 64;
    }
    __syncthreads();
#pragma unroll
    for (int kk = 0; kk < 2; kk++) {
      int cb = (kk * 4 + (lane >> 4)) * 128;
      short8 a[4], b[4];
#pragma unroll
      for (int mt = 0; mt < 4; mt++)
        a[mt] = *(const short8*)&lA[(cb + wm + mt * 16 + (lane & 15)) * 8];
#pragma unroll
      for (int nt = 0; nt < 4; nt++)
        b[nt] = *(const short8*)&lB[(cb + wn + nt * 16 + (lane & 15)) * 8];
#pragma unroll
      for (int mt = 0; mt < 4; mt++)
#pragma unroll
        for (int nt = 0; nt < 4; nt++)
          acc[mt][nt] = __builtin_amdgcn_mfma_f32_16x16x32_bf16(a[mt], b[nt], acc[mt][nt], 0, 0, 0);
    }
  }
#pragma unroll
  for (int mt = 0; mt < 4; mt++)
#pragma unroll
    for (int nt = 0; nt < 4; nt++)
#pragma unroll
      for (int r = 0; r < 4; r++) {
        int row = wm + mt * 16 + ((lane >> 4) << 2) + r;
        int col = blockIdx.x * 128 + wn + nt * 16 + (lane & 15);
        float v = acc[mt][nt][r];
        if (idx) {
          atomicAdd(&Y[(size_t)sIdx[row] * DIM + col], v * sSc[row]);
        } else {
          Y[(size_t)(mbase + blockIdx.y * 128 + row) * DIM + col] = v;
        }
      }
}

// ---------------- host ----------------
extern "C" void kernel_launch(void* const* d_in, const int* in_sizes, int n_in,
                              void* d_out, int out_size, void* d_ws, size_t ws_size,
                              hipStream_t stream) {
  (void)in_sizes; (void)n_in; (void)out_size;
  const float* hs  = (const float*)d_in[0];
  const float* gw  = (const float*)d_in[1];
  const float* Wg  = (const float*)d_in[2];
  const float* Wu  = (const float*)d_in[3];
  const float* Wd  = (const float*)d_in[4];
  const float* Wsg = (const float*)d_in[5];
  const float* Wsu = (const float*)d_in[6];
  const float* Wsd = (const float*)d_in[7];
  float* Y = (float*)d_out;

  char* p = (char*)d_ws;
  auto carve = [&](size_t bytes) {
    char* r = p;
    p += (bytes + 255) & ~(size_t)255;
    return r;
  };
  ushort* Xb   = (ushort*)carve((size_t)N_TOK * DIM * 2);
  ushort* Wgb  = (ushort*)carve((size_t)NEXP * FEXP * DIM * 2);
  ushort* Wub  = (ushort*)carve((size_t)NEXP * FEXP * DIM * 2);
  ushort* Wdb  = (ushort*)carve((size_t)NEXP * DIM * FEXP * 2);
  ushort* Wsgb = (ushort*)carve((size_t)FSH * DIM * 2);
  ushort* Wsub = (ushort*)carve((size_t)FSH * DIM * 2);
  ushort* Wsdb = (ushort*)carve((size_t)DIM * FSH * 2);
  float*  scF  = (float*)carve((size_t)NEXP * N_TOK * 4);
  double* scD  = (double*)carve((size_t)NEXP * N_TOK * 8);
  int*    idx  = (int*)carve((size_t)NEXP * CAP * 4);
  float*  wsc  = (float*)carve((size_t)NEXP * CAP * 4);
  size_t used = (size_t)(p - (char*)d_ws);
  size_t hbytes = ws_size > used ? ws_size - used : 0;
  ushort* Hbuf = (ushort*)p;

  auto cvt = [&](const float* a, ushort* b, size_t n) {
    int n4 = (int)(n / 4);
    cvt_kernel<<<(n4 + 255) / 256, 256, 0, stream>>>(a, b, n4);
  };
  cvt(hs,  Xb,   (size_t)N_TOK * DIM);
  cvt(Wg,  Wgb,  (size_t)NEXP * FEXP * DIM);
  cvt(Wu,  Wub,  (size_t)NEXP * FEXP * DIM);
  cvt(Wd,  Wdb,  (size_t)NEXP * DIM * FEXP);
  cvt(Wsg, Wsgb, (size_t)FSH * DIM);
  cvt(Wsu, Wsub, (size_t)FSH * DIM);
  cvt(Wsd, Wsdb, (size_t)DIM * FSH);

  gate_kernel<<<N_TOK / 16, 256, 0, stream>>>(hs, gw, scF, scD);
  select_kernel<<<NEXP, 1024, 0, stream>>>(scF, scD, idx, wsc);

  // shared expert first: plain stores initialize Y (poisoned 0xAA) before expert atomics
  size_t maxRowsSh = hbytes / ((size_t)FSH * 2);
  int mcSh = (int)(maxRowsSh > (size_t)N_TOK ? (size_t)N_TOK : maxRowsSh);
  mcSh = (mcSh / 128) * 128;
  if (mcSh < 128) mcSh = 128;
  for (int mb = 0; mb < N_TOK; mb += mcSh) {
    int mc = (N_TOK - mb) < mcSh ? (N_TOK - mb) : mcSh;
    gemm_up_t<0><<<dim3(FSH / 128, mc / 128, 1), 256, 0, stream>>>(
        Xb, (const int*)0, Wsgb, Wsub, Hbuf, DIM, FSH, mb, 0, 0, 0);
    gemm_down_t<0><<<dim3(6, mc / 128, 1), 256, 0, stream>>>(
        Hbuf, Wsdb, Y, (const int*)0, (const float*)0, FSH, mb, 0, 0, 0);
  }

  // routed experts: z-grouped launches, group size G sized to fit H in hbytes.
  size_t perExpH = (size_t)CAP * FEXP * 2;  // 25.2 MB per expert
  int G = (int)(hbytes / perExpH);
  if (G > NEXP) G = NEXP;
  if (G >= 1) {
    for (int e0 = 0; e0 < NEXP; e0 += G) {
      int g = (NEXP - e0) < G ? (NEXP - e0) : G;
      gemm_up_t<1><<<dim3(FEXP / 128, CAP / 128, g), 256, 0, stream>>>(
          Xb, idx + (size_t)e0 * CAP, Wgb + (size_t)e0 * FEXP * DIM,
          Wub + (size_t)e0 * FEXP * DIM, Hbuf, DIM, FEXP, 0,
          (long long)CAP, (long long)FEXP * DIM, (long long)CAP * FEXP);
      gemm_down_t<1><<<dim3(6, CAP / 128, g), 256, 0, stream>>>(
          Hbuf, Wdb + (size_t)e0 * DIM * FEXP, Y, idx + (size_t)e0 * CAP,
          wsc + (size_t)e0 * CAP, FEXP, 0,
          (long long)CAP * FEXP, (long long)DIM * FEXP, (long long)CAP);
    }
  } else {
    // tiny-ws fallback: per-expert, M-chunked
    size_t maxRowsE = hbytes / ((size_t)FEXP * 2);
    int mcE = (int)(maxRowsE > (size_t)CAP ? (size_t)CAP : maxRowsE);
    mcE = (mcE / 128) * 128;
    if (mcE < 128) mcE = 128;
    for (int e = 0; e < NEXP; e++) {
      for (int mb = 0; mb < CAP; mb += mcE) {
        int mc = (CAP - mb) < mcE ? (CAP - mb) : mcE;
        gemm_up_t<1><<<dim3(FEXP / 128, mc / 128, 1), 256, 0, stream>>>(
            Xb, idx + (size_t)e * CAP, Wgb + (size_t)e * FEXP * DIM,
            Wub + (size_t)e * FEXP * DIM, Hbuf, DIM, FEXP, mb, 0, 0, 0);
        gemm_down_t<1><<<dim3(6, mc / 128, 1), 256, 0, stream>>>(
            Hbuf, Wdb + (size_t)e * DIM * FEXP, Y, idx + (size_t)e * CAP,
            wsc + (size_t)e * CAP, FEXP, mb, 0, 0, 0);
      }
    }
  }
}